// Round 4
// baseline (829.541 us; speedup 1.0000x reference)
//
#include <hip/hip_runtime.h>
#include <hip/hip_fp16.h>
#include <math.h>

// ---------------------------------------------------------------------------
// GCN autoencoder: 4 layers (12->16->8->16->12), N=200K nodes, E=5M edges.
//
// Round 4: gathers were HBM-random-line bound (240 MB fetch each) because the
// 12.8 MB fp32 xls table thrashes the 4 MB per-XCD L2. Fix: fp16 xls + split
// features into physically separate chunk tables (<=3.2 MB each, L2-resident)
// and run one edge pass per chunk. Gather is now thread-per-node with one
// vector load per edge.
//
//   xls[i] = fp16( (h[i] @ W) * dis[i] )      (chunked tables)
//   agg[i] = dis[i] * ( xls[i] + sum_{e in in(i)} xls[col[e]] )
// ---------------------------------------------------------------------------

#define NODES_PER_BUCKET 256   // bucket id = dst >> 8
#define MAX_NB 1024            // supports N <= 262144
#define BIN_CHUNK 16384        // edges per workgroup in bin_kernel
#define MAXB 9216              // LDS col staging capacity (avg bucket ~6400)

__global__ __launch_bounds__(256) void hist_kernel(const int* __restrict__ dst,
                                                   int* __restrict__ bucket_cnt,
                                                   int E, int NB) {
    __shared__ int h[MAX_NB];
    for (int t = threadIdx.x; t < NB; t += 256) h[t] = 0;
    __syncthreads();
    int stride = gridDim.x * 256;
    for (int e = blockIdx.x * 256 + threadIdx.x; e < E; e += stride)
        atomicAdd(&h[dst[e] >> 8], 1);
    __syncthreads();
    for (int t = threadIdx.x; t < NB; t += 256)
        if (h[t]) atomicAdd(&bucket_cnt[t], h[t]);
}

__global__ __launch_bounds__(1024) void bscan_kernel(const int* __restrict__ bucket_cnt,
                                                     int* __restrict__ bucket_ptr,
                                                     int* __restrict__ bucket_cur,
                                                     int* __restrict__ row_ptr,
                                                     int NB, int N, int E) {
    __shared__ int s[1024];
    int v = (threadIdx.x < (unsigned)NB) ? bucket_cnt[threadIdx.x] : 0;
    s[threadIdx.x] = v;
    __syncthreads();
    for (int off = 1; off < 1024; off <<= 1) {
        int t = (threadIdx.x >= (unsigned)off) ? s[threadIdx.x - off] : 0;
        __syncthreads();
        s[threadIdx.x] += t;
        __syncthreads();
    }
    int excl = s[threadIdx.x] - v;
    if (threadIdx.x < (unsigned)NB) {
        bucket_ptr[threadIdx.x] = excl;
        bucket_cur[threadIdx.x] = excl;
    }
    if (threadIdx.x == 0) { bucket_ptr[NB] = E; row_ptr[N] = E; }
}

// Each workgroup: LDS histogram of its chunk, ONE global atomic per touched
// bucket to reserve a contiguous run, then append 4B packed records
// ((src<<8)|local_dst). Run-contiguous writes fill cache lines.
__global__ __launch_bounds__(256) void bin_kernel(const int* __restrict__ src,
                                                  const int* __restrict__ dst,
                                                  int* __restrict__ bucket_cur,
                                                  unsigned int* __restrict__ binned,
                                                  int E, int NB) {
    __shared__ int h[MAX_NB];
    __shared__ int base[MAX_NB];
    int cbeg = blockIdx.x * BIN_CHUNK;
    int cend = min(cbeg + BIN_CHUNK, E);
    for (int t = threadIdx.x; t < NB; t += 256) h[t] = 0;
    __syncthreads();
    for (int e = cbeg + threadIdx.x; e < cend; e += 256)
        atomicAdd(&h[dst[e] >> 8], 1);
    __syncthreads();
    for (int t = threadIdx.x; t < NB; t += 256) {
        int c = h[t];
        base[t] = c ? atomicAdd(&bucket_cur[t], c) : 0;
    }
    __syncthreads();
    for (int t = threadIdx.x; t < NB; t += 256) h[t] = 0;  // reuse as cursor
    __syncthreads();
    for (int e = cbeg + threadIdx.x; e < cend; e += 256) {
        int d = dst[e];
        int bkt = d >> 8;
        int pos = base[bkt] + atomicAdd(&h[bkt], 1);
        binned[pos] = ((unsigned)src[e] << 8) | (unsigned)(d & 255);
    }
}

// One workgroup per bucket: count per-node degrees in LDS, scan, emit
// row_ptr segment + dis (sequential), scatter src into LDS, flush coalesced.
__global__ __launch_bounds__(256) void csr_bucket_kernel(
    const unsigned int* __restrict__ binned,
    const int* __restrict__ bucket_ptr,
    int* __restrict__ row_ptr, float* __restrict__ dis,
    int* __restrict__ col, int N) {
    __shared__ int cnt[256];
    __shared__ int cur[256];
    __shared__ int colbuf[MAXB];
    int b = blockIdx.x;
    int nbase = b << 8;
    int nlocal = min(256, N - nbase);
    int beg = bucket_ptr[b];
    int end = bucket_ptr[b + 1];
    int bsize = end - beg;

    cnt[threadIdx.x] = 0;
    __syncthreads();
    for (int k = threadIdx.x; k < bsize; k += 256)
        atomicAdd(&cnt[binned[beg + k] & 255u], 1);
    __syncthreads();
    int v = cnt[threadIdx.x];
    cur[threadIdx.x] = v;
    __syncthreads();
    for (int off = 1; off < 256; off <<= 1) {
        int t = (threadIdx.x >= (unsigned)off) ? cur[threadIdx.x - off] : 0;
        __syncthreads();
        cur[threadIdx.x] += t;
        __syncthreads();
    }
    int excl = cur[threadIdx.x] - v;
    if ((int)threadIdx.x < nlocal) {
        row_ptr[nbase + threadIdx.x] = beg + excl;
        dis[nbase + threadIdx.x] = 1.0f / sqrtf((float)(v + 1));  // +1 self-loop
    }
    __syncthreads();
    cur[threadIdx.x] = excl;
    __syncthreads();
    if (bsize <= MAXB) {
        for (int k = threadIdx.x; k < bsize; k += 256) {
            unsigned rec = binned[beg + k];
            int pos = atomicAdd(&cur[rec & 255u], 1);
            colbuf[pos] = (int)(rec >> 8);
        }
        __syncthreads();
        for (int k = threadIdx.x; k < bsize; k += 256) col[beg + k] = colbuf[k];
    } else {  // never expected for random input; correct slow path
        for (int k = threadIdx.x; k < bsize; k += 256) {
            unsigned rec = binned[beg + k];
            int pos = atomicAdd(&cur[rec & 255u], 1);
            col[beg + pos] = (int)(rec >> 8);
        }
    }
}

// PREACT: 0 = raw input (layer 1), 1 = bias + relu, 2 = bias only
// Writes fp16 xls split into OUT/C chunk tables of C features each:
//   chunk c lives at xls + c*N*C (half units), record i*C + f.
template <int IN, int OUT, int C, int PREACT>
__global__ __launch_bounds__(256) void transform_kernel(
    const float* __restrict__ hin, const float* __restrict__ bias_prev,
    const float* __restrict__ W, const float* __restrict__ dis,
    __half* __restrict__ xls, int N) {
    __shared__ float sW[IN * OUT];
    __shared__ float sB[IN];
    for (int t = threadIdx.x; t < IN * OUT; t += blockDim.x) sW[t] = W[t];
    if (PREACT != 0) {
        for (int t = threadIdx.x; t < IN; t += blockDim.x) sB[t] = bias_prev[t];
    }
    __syncthreads();
    int i = blockIdx.x * blockDim.x + threadIdx.x;
    if (i >= N) return;

    float h[IN];
#pragma unroll
    for (int k = 0; k < IN; k++) {
        float v = hin[i * IN + k];
        if (PREACT != 0) {
            v += sB[k];
            if (PREACT == 1) v = fmaxf(v, 0.0f);
        }
        h[k] = v;
    }
    float d = dis[i];
    float o[OUT];
#pragma unroll
    for (int f = 0; f < OUT; f++) {
        float acc = 0.0f;
#pragma unroll
        for (int k = 0; k < IN; k++) acc = fmaf(h[k], sW[k * OUT + f], acc);
        o[f] = acc * d;  // pre-scaled by dis[i]
    }
    constexpr int NCH = OUT / C;
    constexpr int P = C / 2;
    __half2* x2 = (__half2*)xls;
#pragma unroll
    for (int c = 0; c < NCH; c++) {
#pragma unroll
        for (int k = 0; k < P; k++) {
            x2[(size_t)c * N * P + (size_t)i * P + k] =
                __floats2half2_rn(o[c * C + 2 * k], o[c * C + 2 * k + 1]);
        }
    }
}

// Thread-per-node pull gather over one C-feature chunk table (L2-resident).
// One col read + one 2C-byte vector read per edge.
template <int C, int F, int COFF>
__global__ __launch_bounds__(256) void gather_kernel(
    const int* __restrict__ row_ptr, const int* __restrict__ col,
    const float* __restrict__ dis, const __half* __restrict__ xls,
    float* __restrict__ agg, int N) {
    int i = blockIdx.x * blockDim.x + threadIdx.x;
    if (i >= N) return;
    constexpr int P = C / 2;
    const __half2* x2 = (const __half2*)xls;
    float2 acc[P];
#pragma unroll
    for (int k = 0; k < P; k++) acc[k] = __half22float2(x2[(size_t)i * P + k]);  // self-loop
    int beg = row_ptr[i];
    int end = row_ptr[i + 1];
    for (int e = beg; e < end; e++) {
        int c = col[e];
#pragma unroll
        for (int k = 0; k < P; k++) {
            float2 v = __half22float2(x2[(size_t)c * P + k]);
            acc[k].x += v.x;
            acc[k].y += v.y;
        }
    }
    float d = dis[i];
    float2* ap = (float2*)(agg + (size_t)i * F + COFF);
#pragma unroll
    for (int k = 0; k < P; k++) ap[k] = make_float2(acc[k].x * d, acc[k].y * d);
}

__global__ void final_kernel(const float* __restrict__ agg,
                             const float* __restrict__ b,
                             float* __restrict__ out, int total, int F) {
    int idx = blockIdx.x * blockDim.x + threadIdx.x;
    if (idx < total) {
        int f = idx % F;
        float v = agg[idx] + b[f];
        out[idx] = 1.0f / (1.0f + expf(-v));
    }
}

static inline size_t align_up(size_t v, size_t a) { return (v + a - 1) & ~(a - 1); }

extern "C" void kernel_launch(void* const* d_in, const int* in_sizes, int n_in,
                              void* d_out, int out_size, void* d_ws, size_t ws_size,
                              hipStream_t stream) {
    const float* x  = (const float*)d_in[0];
    const int*   ei = (const int*)d_in[1];
    const float* W1 = (const float*)d_in[2];
    const float* b1 = (const float*)d_in[3];
    const float* W2 = (const float*)d_in[4];
    const float* b2 = (const float*)d_in[5];
    const float* W3 = (const float*)d_in[6];
    const float* b3 = (const float*)d_in[7];
    const float* W4 = (const float*)d_in[8];
    const float* b4 = (const float*)d_in[9];
    float* out = (float*)d_out;

    const int N = in_sizes[0] / 12;
    const int E = in_sizes[1] / 2;
    const int* src = ei;       // edge_index[0]
    const int* dst = ei + E;   // edge_index[1]
    const int NB = (N + NODES_PER_BUCKET - 1) / NODES_PER_BUCKET;  // 782

    // Workspace carve-up (~60 MB)
    char* ws = (char*)d_ws;
    size_t off = 0;
    int* bucket_cnt = (int*)(ws + off);   off = align_up(off + (size_t)NB * 4, 256);
    int* bucket_ptr = (int*)(ws + off);   off = align_up(off + (size_t)(NB + 1) * 4, 256);
    int* bucket_cur = (int*)(ws + off);   off = align_up(off + (size_t)NB * 4, 256);
    int* row_ptr = (int*)(ws + off);      off = align_up(off + (size_t)(N + 1) * 4, 256);
    float* dis = (float*)(ws + off);      off = align_up(off + (size_t)N * 4, 256);
    unsigned int* binned = (unsigned int*)(ws + off); off = align_up(off + (size_t)E * 4, 256);
    int* col = (int*)(ws + off);          off = align_up(off + (size_t)E * 4, 256);
    __half* xls = (__half*)(ws + off);    off = align_up(off + (size_t)N * 16 * 2, 256);
    float* agg = (float*)(ws + off);      off = align_up(off + (size_t)N * 16 * 4, 256);
    (void)ws_size; (void)n_in; (void)out_size;

    const int B = 256;
    auto blocks = [&](long long n) { return (int)((n + B - 1) / B); };

    // --- CSR build via bucketed counting sort ----------------------------
    hipMemsetAsync(bucket_cnt, 0, (size_t)NB * sizeof(int), stream);
    hist_kernel<<<512, B, 0, stream>>>(dst, bucket_cnt, E, NB);
    bscan_kernel<<<1, 1024, 0, stream>>>(bucket_cnt, bucket_ptr, bucket_cur, row_ptr, NB, N, E);
    bin_kernel<<<(E + BIN_CHUNK - 1) / BIN_CHUNK, B, 0, stream>>>(src, dst, bucket_cur, binned, E, NB);
    csr_bucket_kernel<<<NB, B, 0, stream>>>(binned, bucket_ptr, row_ptr, dis, col, N);

    // Chunk-table base helper (half units): chunk c of size C lives at c*N*C
    __half* x_c0 = xls;
    __half* x_c8 = xls + (size_t)N * 8;  // second chunk for C=8 layers
    __half* x_c6 = xls + (size_t)N * 6;  // second chunk for C=6 layer

    // --- Layer 1: x(12) @ W1 -> 16 (chunks 2x8) --------------------------
    transform_kernel<12, 16, 8, 0><<<blocks(N), B, 0, stream>>>(x, nullptr, W1, dis, xls, N);
    gather_kernel<8, 16, 0><<<blocks(N), B, 0, stream>>>(row_ptr, col, dis, x_c0, agg, N);
    gather_kernel<8, 16, 8><<<blocks(N), B, 0, stream>>>(row_ptr, col, dis, x_c8, agg, N);

    // --- Layer 2: relu(agg + b1)(16) @ W2 -> 8 (1x8) ---------------------
    transform_kernel<16, 8, 8, 1><<<blocks(N), B, 0, stream>>>(agg, b1, W2, dis, xls, N);
    gather_kernel<8, 8, 0><<<blocks(N), B, 0, stream>>>(row_ptr, col, dis, x_c0, agg, N);

    // --- Layer 3: (agg + b2)(8) @ W3 -> 16 (2x8, no relu) ----------------
    transform_kernel<8, 16, 8, 2><<<blocks(N), B, 0, stream>>>(agg, b2, W3, dis, xls, N);
    gather_kernel<8, 16, 0><<<blocks(N), B, 0, stream>>>(row_ptr, col, dis, x_c0, agg, N);
    gather_kernel<8, 16, 8><<<blocks(N), B, 0, stream>>>(row_ptr, col, dis, x_c8, agg, N);

    // --- Layer 4: relu(agg + b3)(16) @ W4 -> 12 (chunks 2x6) -------------
    transform_kernel<16, 12, 6, 1><<<blocks(N), B, 0, stream>>>(agg, b3, W4, dis, xls, N);
    gather_kernel<6, 12, 0><<<blocks(N), B, 0, stream>>>(row_ptr, col, dis, x_c0, agg, N);
    gather_kernel<6, 12, 6><<<blocks(N), B, 0, stream>>>(row_ptr, col, dis, x_c6, agg, N);

    // --- Epilogue: sigmoid(agg + b4) -> out ------------------------------
    final_kernel<<<blocks((long long)N * 12), B, 0, stream>>>(agg, b4, out, N * 12, 12);
}

// Round 5
// 599.454 us; speedup vs baseline: 1.3838x; 1.3838x over previous
//
#include <hip/hip_runtime.h>
#include <hip/hip_fp16.h>
#include <math.h>

// ---------------------------------------------------------------------------
// GCN autoencoder: 4 layers (12->16->8->16->12), N=200K nodes, E=5M edges.
//
// Round 5:
//  * bin_kernel was latency-starved (305 blocks, 10% occ) with short bucket
//    runs (84 B). Now: 1024-node buckets (NB=196, 42-rec runs per 4096-edge
//    chunk), 1221 blocks, dst cached in VGPRs (single read pass).
//  * csr_bucket rebuilt as half-bucket WGs (392 x 512 thr, <64 KB LDS).
//  * gather unrolled x4 for 4 outstanding table loads per thread.
// Pipeline: hist -> bscan -> bin -> csr_bucket -> per layer
//   (transform: xls[i]=fp16((h@W)*dis), chunked tables <=3.2MB, L2-resident;
//    gather: agg[i]=dis*(xls[i]+sum xls[col]) per chunk).
// ---------------------------------------------------------------------------

#define NPB 1024               // nodes per bucket; bucket id = dst >> 10
#define MAX_NB 256             // supports N <= 262144
#define BIN_CHUNK 4096         // edges per workgroup in bin_kernel
#define EPT (BIN_CHUNK / 256)  // edges per thread in bin_kernel (16)
#define MAXB 14336             // LDS col staging (half-bucket avg ~12800)

__global__ __launch_bounds__(256) void hist_kernel(const int* __restrict__ dst,
                                                   int* __restrict__ bucket_cnt,
                                                   int E, int NB) {
    __shared__ int h[MAX_NB];
    for (int t = threadIdx.x; t < NB; t += 256) h[t] = 0;
    __syncthreads();
    int stride = gridDim.x * 256;
    for (int e = blockIdx.x * 256 + threadIdx.x; e < E; e += stride)
        atomicAdd(&h[dst[e] >> 10], 1);
    __syncthreads();
    for (int t = threadIdx.x; t < NB; t += 256)
        if (h[t]) atomicAdd(&bucket_cnt[t], h[t]);
}

__global__ __launch_bounds__(1024) void bscan_kernel(const int* __restrict__ bucket_cnt,
                                                     int* __restrict__ bucket_ptr,
                                                     int* __restrict__ bucket_cur,
                                                     int* __restrict__ row_ptr,
                                                     int NB, int N, int E) {
    __shared__ int s[1024];
    int v = (threadIdx.x < (unsigned)NB) ? bucket_cnt[threadIdx.x] : 0;
    s[threadIdx.x] = v;
    __syncthreads();
    for (int off = 1; off < 1024; off <<= 1) {
        int t = (threadIdx.x >= (unsigned)off) ? s[threadIdx.x - off] : 0;
        __syncthreads();
        s[threadIdx.x] += t;
        __syncthreads();
    }
    int excl = s[threadIdx.x] - v;
    if (threadIdx.x < (unsigned)NB) {
        bucket_ptr[threadIdx.x] = excl;
        bucket_cur[threadIdx.x] = excl;
    }
    if (threadIdx.x == 0) { bucket_ptr[NB] = E; row_ptr[N] = E; }
}

// Per-chunk LDS histogram -> one global atomic per touched bucket reserves a
// contiguous run -> append packed records ((src<<10)|local_dst). dst values
// are cached in VGPRs so global dst is read exactly once.
__global__ __launch_bounds__(256) void bin_kernel(const int* __restrict__ src,
                                                  const int* __restrict__ dst,
                                                  int* __restrict__ bucket_cur,
                                                  unsigned int* __restrict__ binned,
                                                  int E, int NB) {
    __shared__ int h[MAX_NB];
    __shared__ int base[MAX_NB];
    int cbeg = blockIdx.x * BIN_CHUNK;
    int cend = min(cbeg + BIN_CHUNK, E);
    for (int t = threadIdx.x; t < NB; t += 256) h[t] = 0;
    __syncthreads();
    int myd[EPT];
#pragma unroll
    for (int j = 0; j < EPT; j++) {
        int e = cbeg + threadIdx.x + j * 256;
        if (e < cend) {
            myd[j] = dst[e];
            atomicAdd(&h[myd[j] >> 10], 1);
        }
    }
    __syncthreads();
    for (int t = threadIdx.x; t < NB; t += 256) {
        int c = h[t];
        base[t] = c ? atomicAdd(&bucket_cur[t], c) : 0;
    }
    __syncthreads();
    for (int t = threadIdx.x; t < NB; t += 256) h[t] = 0;  // reuse as cursor
    __syncthreads();
#pragma unroll
    for (int j = 0; j < EPT; j++) {
        int e = cbeg + threadIdx.x + j * 256;
        if (e < cend) {
            int d = myd[j];
            int bkt = d >> 10;
            int pos = base[bkt] + atomicAdd(&h[bkt], 1);
            binned[pos] = ((unsigned)src[e] << 10) | (unsigned)(d & 1023);
        }
    }
}

// One WG per HALF bucket (512 nodes): filter the bucket's records by the
// local-id high bit, per-node count + scan in LDS, emit row_ptr/dis
// (sequential), scatter src into LDS colbuf, flush coalesced.
__global__ __launch_bounds__(512) void csr_bucket_kernel(
    const unsigned int* __restrict__ binned,
    const int* __restrict__ bucket_ptr,
    int* __restrict__ row_ptr, float* __restrict__ dis,
    int* __restrict__ col, int N) {
    __shared__ int cnt[512];
    __shared__ int cur[512];
    __shared__ int colbuf[MAXB];
    __shared__ int c0;      // records of this bucket with local < 512
    __shared__ int tot_s;   // records belonging to this half
    int b = blockIdx.x >> 1;
    int half = blockIdx.x & 1;
    int nbase = b * NPB + half * 512;
    int nlocal = min(512, N - nbase);  // may be <= 0 for trailing half
    int beg = bucket_ptr[b];
    int end = bucket_ptr[b + 1];
    int bsize = end - beg;
    int tid = threadIdx.x;

    cnt[tid] = 0;
    if (tid == 0) c0 = 0;
    __syncthreads();
    for (int k = tid; k < bsize; k += 512) {
        unsigned rec = binned[beg + k];
        int loc = (int)(rec & 1023u);
        if ((loc >> 9) == half) atomicAdd(&cnt[loc & 511], 1);
        unsigned long long m = __ballot(loc < 512);
        if ((tid & 63) == 0) atomicAdd(&c0, (int)__popcll(m));
    }
    __syncthreads();
    int v = cnt[tid];
    cur[tid] = v;
    __syncthreads();
    for (int off = 1; off < 512; off <<= 1) {
        int t = (tid >= off) ? cur[tid - off] : 0;
        __syncthreads();
        cur[tid] += t;
        __syncthreads();
    }
    int excl = cur[tid] - v;
    if (tid == 511) tot_s = cur[511];
    __syncthreads();
    int base_col = beg + (half ? c0 : 0);
    int tot = tot_s;
    if (tid < nlocal) {
        row_ptr[nbase + tid] = base_col + excl;
        dis[nbase + tid] = 1.0f / sqrtf((float)(v + 1));  // +1 self-loop
    }
    __syncthreads();
    cur[tid] = excl;
    __syncthreads();
    if (tot <= MAXB) {
        for (int k = tid; k < bsize; k += 512) {
            unsigned rec = binned[beg + k];
            int loc = (int)(rec & 1023u);
            if ((loc >> 9) == half) {
                int pos = atomicAdd(&cur[loc & 511], 1);
                colbuf[pos] = (int)(rec >> 10);
            }
        }
        __syncthreads();
        for (int k = tid; k < tot; k += 512) col[base_col + k] = colbuf[k];
    } else {  // statistical impossibility for this input; correctness fallback
        for (int k = tid; k < bsize; k += 512) {
            unsigned rec = binned[beg + k];
            int loc = (int)(rec & 1023u);
            if ((loc >> 9) == half) {
                int pos = atomicAdd(&cur[loc & 511], 1);
                col[base_col + pos] = (int)(rec >> 10);
            }
        }
    }
}

// PREACT: 0 = raw input (layer 1), 1 = bias + relu, 2 = bias only
// Writes fp16 xls split into OUT/C chunk tables of C features each.
template <int IN, int OUT, int C, int PREACT>
__global__ __launch_bounds__(256) void transform_kernel(
    const float* __restrict__ hin, const float* __restrict__ bias_prev,
    const float* __restrict__ W, const float* __restrict__ dis,
    __half* __restrict__ xls, int N) {
    __shared__ float sW[IN * OUT];
    __shared__ float sB[IN];
    for (int t = threadIdx.x; t < IN * OUT; t += blockDim.x) sW[t] = W[t];
    if (PREACT != 0) {
        for (int t = threadIdx.x; t < IN; t += blockDim.x) sB[t] = bias_prev[t];
    }
    __syncthreads();
    int i = blockIdx.x * blockDim.x + threadIdx.x;
    if (i >= N) return;

    float h[IN];
#pragma unroll
    for (int k = 0; k < IN; k++) {
        float v = hin[i * IN + k];
        if (PREACT != 0) {
            v += sB[k];
            if (PREACT == 1) v = fmaxf(v, 0.0f);
        }
        h[k] = v;
    }
    float d = dis[i];
    float o[OUT];
#pragma unroll
    for (int f = 0; f < OUT; f++) {
        float acc = 0.0f;
#pragma unroll
        for (int k = 0; k < IN; k++) acc = fmaf(h[k], sW[k * OUT + f], acc);
        o[f] = acc * d;  // pre-scaled by dis[i]
    }
    constexpr int NCH = OUT / C;
    constexpr int P = C / 2;
    __half2* x2 = (__half2*)xls;
#pragma unroll
    for (int c = 0; c < NCH; c++) {
#pragma unroll
        for (int k = 0; k < P; k++) {
            x2[(size_t)c * N * P + (size_t)i * P + k] =
                __floats2half2_rn(o[c * C + 2 * k], o[c * C + 2 * k + 1]);
        }
    }
}

// Thread-per-node pull gather over one C-feature chunk table (L2-resident).
// Edge loop unrolled x4: 4 col reads, then 4 independent table loads in
// flight before any accumulate.
template <int C, int F, int COFF>
__global__ __launch_bounds__(256) void gather_kernel(
    const int* __restrict__ row_ptr, const int* __restrict__ col,
    const float* __restrict__ dis, const __half* __restrict__ xls,
    float* __restrict__ agg, int N) {
    int i = blockIdx.x * blockDim.x + threadIdx.x;
    if (i >= N) return;
    constexpr int P = C / 2;
    const __half2* x2 = (const __half2*)xls;
    float2 acc[P];
#pragma unroll
    for (int k = 0; k < P; k++) acc[k] = __half22float2(x2[(size_t)i * P + k]);
    int e = row_ptr[i];
    int end = row_ptr[i + 1];
    for (; e + 4 <= end; e += 4) {
        int c0 = col[e], c1 = col[e + 1], c2 = col[e + 2], c3 = col[e + 3];
        __half2 t0[P], t1[P], t2[P], t3[P];
#pragma unroll
        for (int k = 0; k < P; k++) t0[k] = x2[(size_t)c0 * P + k];
#pragma unroll
        for (int k = 0; k < P; k++) t1[k] = x2[(size_t)c1 * P + k];
#pragma unroll
        for (int k = 0; k < P; k++) t2[k] = x2[(size_t)c2 * P + k];
#pragma unroll
        for (int k = 0; k < P; k++) t3[k] = x2[(size_t)c3 * P + k];
#pragma unroll
        for (int k = 0; k < P; k++) {
            float2 a = __half22float2(t0[k]), bb = __half22float2(t1[k]);
            float2 cc = __half22float2(t2[k]), dd = __half22float2(t3[k]);
            acc[k].x += (a.x + bb.x) + (cc.x + dd.x);
            acc[k].y += (a.y + bb.y) + (cc.y + dd.y);
        }
    }
    for (; e < end; e++) {
        int c = col[e];
#pragma unroll
        for (int k = 0; k < P; k++) {
            float2 vv = __half22float2(x2[(size_t)c * P + k]);
            acc[k].x += vv.x;
            acc[k].y += vv.y;
        }
    }
    float d = dis[i];
    float2* ap = (float2*)(agg + (size_t)i * F + COFF);
#pragma unroll
    for (int k = 0; k < P; k++) ap[k] = make_float2(acc[k].x * d, acc[k].y * d);
}

__global__ void final_kernel(const float* __restrict__ agg,
                             const float* __restrict__ b,
                             float* __restrict__ out, int total, int F) {
    int idx = blockIdx.x * blockDim.x + threadIdx.x;
    if (idx < total) {
        int f = idx % F;
        float v = agg[idx] + b[f];
        out[idx] = 1.0f / (1.0f + expf(-v));
    }
}

static inline size_t align_up(size_t v, size_t a) { return (v + a - 1) & ~(a - 1); }

extern "C" void kernel_launch(void* const* d_in, const int* in_sizes, int n_in,
                              void* d_out, int out_size, void* d_ws, size_t ws_size,
                              hipStream_t stream) {
    const float* x  = (const float*)d_in[0];
    const int*   ei = (const int*)d_in[1];
    const float* W1 = (const float*)d_in[2];
    const float* b1 = (const float*)d_in[3];
    const float* W2 = (const float*)d_in[4];
    const float* b2 = (const float*)d_in[5];
    const float* W3 = (const float*)d_in[6];
    const float* b3 = (const float*)d_in[7];
    const float* W4 = (const float*)d_in[8];
    const float* b4 = (const float*)d_in[9];
    float* out = (float*)d_out;

    const int N = in_sizes[0] / 12;
    const int E = in_sizes[1] / 2;
    const int* src = ei;       // edge_index[0]
    const int* dst = ei + E;   // edge_index[1]
    const int NB = (N + NPB - 1) / NPB;  // 196

    // Workspace carve-up (~62 MB)
    char* ws = (char*)d_ws;
    size_t off = 0;
    int* bucket_cnt = (int*)(ws + off);   off = align_up(off + (size_t)NB * 4, 256);
    int* bucket_ptr = (int*)(ws + off);   off = align_up(off + (size_t)(NB + 1) * 4, 256);
    int* bucket_cur = (int*)(ws + off);   off = align_up(off + (size_t)NB * 4, 256);
    int* row_ptr = (int*)(ws + off);      off = align_up(off + (size_t)(N + 1) * 4, 256);
    float* dis = (float*)(ws + off);      off = align_up(off + (size_t)N * 4, 256);
    unsigned int* binned = (unsigned int*)(ws + off); off = align_up(off + (size_t)E * 4, 256);
    int* col = (int*)(ws + off);          off = align_up(off + (size_t)E * 4, 256);
    __half* xls = (__half*)(ws + off);    off = align_up(off + (size_t)N * 16 * 2, 256);
    float* agg = (float*)(ws + off);      off = align_up(off + (size_t)N * 16 * 4, 256);
    (void)ws_size; (void)n_in; (void)out_size;

    const int B = 256;
    auto blocks = [&](long long n) { return (int)((n + B - 1) / B); };

    // --- CSR build via bucketed counting sort ----------------------------
    hipMemsetAsync(bucket_cnt, 0, (size_t)NB * sizeof(int), stream);
    hist_kernel<<<512, B, 0, stream>>>(dst, bucket_cnt, E, NB);
    bscan_kernel<<<1, 1024, 0, stream>>>(bucket_cnt, bucket_ptr, bucket_cur, row_ptr, NB, N, E);
    bin_kernel<<<(E + BIN_CHUNK - 1) / BIN_CHUNK, B, 0, stream>>>(src, dst, bucket_cur, binned, E, NB);
    csr_bucket_kernel<<<NB * 2, 512, 0, stream>>>(binned, bucket_ptr, row_ptr, dis, col, N);

    // Chunk-table bases (half units): chunk c of size C lives at c*N*C
    __half* x_c0 = xls;
    __half* x_c8 = xls + (size_t)N * 8;  // second chunk for C=8 layers
    __half* x_c6 = xls + (size_t)N * 6;  // second chunk for C=6 layer

    // --- Layer 1: x(12) @ W1 -> 16 (chunks 2x8) --------------------------
    transform_kernel<12, 16, 8, 0><<<blocks(N), B, 0, stream>>>(x, nullptr, W1, dis, xls, N);
    gather_kernel<8, 16, 0><<<blocks(N), B, 0, stream>>>(row_ptr, col, dis, x_c0, agg, N);
    gather_kernel<8, 16, 8><<<blocks(N), B, 0, stream>>>(row_ptr, col, dis, x_c8, agg, N);

    // --- Layer 2: relu(agg + b1)(16) @ W2 -> 8 (1x8) ---------------------
    transform_kernel<16, 8, 8, 1><<<blocks(N), B, 0, stream>>>(agg, b1, W2, dis, xls, N);
    gather_kernel<8, 8, 0><<<blocks(N), B, 0, stream>>>(row_ptr, col, dis, x_c0, agg, N);

    // --- Layer 3: (agg + b2)(8) @ W3 -> 16 (2x8, no relu) ----------------
    transform_kernel<8, 16, 8, 2><<<blocks(N), B, 0, stream>>>(agg, b2, W3, dis, xls, N);
    gather_kernel<8, 16, 0><<<blocks(N), B, 0, stream>>>(row_ptr, col, dis, x_c0, agg, N);
    gather_kernel<8, 16, 8><<<blocks(N), B, 0, stream>>>(row_ptr, col, dis, x_c8, agg, N);

    // --- Layer 4: relu(agg + b3)(16) @ W4 -> 12 (chunks 2x6) -------------
    transform_kernel<16, 12, 6, 1><<<blocks(N), B, 0, stream>>>(agg, b3, W4, dis, xls, N);
    gather_kernel<6, 12, 0><<<blocks(N), B, 0, stream>>>(row_ptr, col, dis, x_c0, agg, N);
    gather_kernel<6, 12, 6><<<blocks(N), B, 0, stream>>>(row_ptr, col, dis, x_c6, agg, N);

    // --- Epilogue: sigmoid(agg + b4) -> out ------------------------------
    final_kernel<<<blocks((long long)N * 12), B, 0, stream>>>(agg, b4, out, N * 12, 12);
}

// Round 6
// 542.803 us; speedup vs baseline: 1.5283x; 1.1044x over previous
//
#include <hip/hip_runtime.h>
#include <hip/hip_fp16.h>
#include <math.h>

// ---------------------------------------------------------------------------
// GCN autoencoder: 4 layers (12->16->8->16->12), N=200K nodes, E=5M edges.
//
// Round 6:
//  * bin_kernel: block-level LDS counting sort (hist -> LDS scan -> LDS
//    scatter -> coalesced flush). Replaces 5M random global dword stores
//    (TCC write-port bound, 98 MB write-amp) with sequential run writes.
//  * gather: 2 threads per node (even/odd edges), unroll x4 each, pair
//    combined via __shfl_xor -> 2x resident waves, ~8 loads in flight/node.
// Pipeline: hist -> bscan -> bin(LDS sort) -> csr_bucket -> per layer
//   (transform: xls[i]=fp16((h@W)*dis), chunk tables <=3.2MB L2-resident;
//    gather: agg[i]=dis*(xls[i]+sum xls[col]) per chunk).
// ---------------------------------------------------------------------------

#define NPB 1024               // nodes per bucket; bucket id = dst >> 10
#define MAX_NB 256             // supports N <= 262144
#define BIN_CHUNK 8192         // edges per workgroup in bin_kernel
#define EPT (BIN_CHUNK / 256)  // edges per thread in bin_kernel (32)
#define MAXB 14336             // LDS col staging (half-bucket avg ~12800)

__global__ __launch_bounds__(256) void hist_kernel(const int* __restrict__ dst,
                                                   int* __restrict__ bucket_cnt,
                                                   int E, int NB) {
    __shared__ int h[MAX_NB];
    for (int t = threadIdx.x; t < NB; t += 256) h[t] = 0;
    __syncthreads();
    int stride = gridDim.x * 256;
    for (int e = blockIdx.x * 256 + threadIdx.x; e < E; e += stride)
        atomicAdd(&h[dst[e] >> 10], 1);
    __syncthreads();
    for (int t = threadIdx.x; t < NB; t += 256)
        if (h[t]) atomicAdd(&bucket_cnt[t], h[t]);
}

__global__ __launch_bounds__(1024) void bscan_kernel(const int* __restrict__ bucket_cnt,
                                                     int* __restrict__ bucket_ptr,
                                                     int* __restrict__ bucket_cur,
                                                     int* __restrict__ row_ptr,
                                                     int NB, int N, int E) {
    __shared__ int s[1024];
    int v = (threadIdx.x < (unsigned)NB) ? bucket_cnt[threadIdx.x] : 0;
    s[threadIdx.x] = v;
    __syncthreads();
    for (int off = 1; off < 1024; off <<= 1) {
        int t = (threadIdx.x >= (unsigned)off) ? s[threadIdx.x - off] : 0;
        __syncthreads();
        s[threadIdx.x] += t;
        __syncthreads();
    }
    int excl = s[threadIdx.x] - v;
    if (threadIdx.x < (unsigned)NB) {
        bucket_ptr[threadIdx.x] = excl;
        bucket_cur[threadIdx.x] = excl;
    }
    if (threadIdx.x == 0) { bucket_ptr[NB] = E; row_ptr[N] = E; }
}

// Block-level LDS counting sort of an 8192-edge chunk:
//   hist -> block scan -> reserve global runs (1 atomic/bucket) ->
//   LDS scatter into bucket order -> fully coalesced flush (binary search
//   slot -> bucket). Records: (src<<10)|local_dst.
__global__ __launch_bounds__(256) void bin_kernel(const int* __restrict__ src,
                                                  const int* __restrict__ dst,
                                                  int* __restrict__ bucket_cur,
                                                  unsigned int* __restrict__ binned,
                                                  int E, int NB) {
    __shared__ int h[MAX_NB];          // hist, then reused as scatter cursor
    __shared__ int scl[MAX_NB + 1];    // block-local exclusive offsets
    __shared__ int base[MAX_NB];       // global run bases
    __shared__ int sscan[256];
    __shared__ unsigned int stage[BIN_CHUNK];  // 32 KB
    int cbeg = blockIdx.x * BIN_CHUNK;
    int cend = min(cbeg + BIN_CHUNK, E);
    int chunk_n = cend - cbeg;
    int tid = threadIdx.x;

    for (int t = tid; t < NB; t += 256) h[t] = 0;
    __syncthreads();
    int myd[EPT];
#pragma unroll
    for (int j = 0; j < EPT; j++) {
        int e = cbeg + tid + j * 256;
        if (e < cend) {
            myd[j] = dst[e];
            atomicAdd(&h[myd[j] >> 10], 1);
        }
    }
    __syncthreads();
    // exclusive scan of h[0..NB) with 256 threads (NB <= 256)
    int v = (tid < NB) ? h[tid] : 0;
    sscan[tid] = v;
    __syncthreads();
    for (int off = 1; off < 256; off <<= 1) {
        int t = (tid >= off) ? sscan[tid - off] : 0;
        __syncthreads();
        sscan[tid] += t;
        __syncthreads();
    }
    if (tid < NB) {
        scl[tid] = sscan[tid] - v;
        base[tid] = v ? atomicAdd(&bucket_cur[tid], v) : 0;
    }
    if (tid == 0) scl[NB] = chunk_n;
    __syncthreads();
    for (int t = tid; t < NB; t += 256) h[t] = 0;  // reuse as cursor
    __syncthreads();
#pragma unroll
    for (int j = 0; j < EPT; j++) {
        int e = cbeg + tid + j * 256;
        if (e < cend) {
            int d = myd[j];
            int bkt = d >> 10;
            int pos = scl[bkt] + atomicAdd(&h[bkt], 1);
            stage[pos] = ((unsigned)src[e] << 10) | (unsigned)(d & 1023);
        }
    }
    __syncthreads();
    // coalesced flush: slot k -> bucket via binary search on scl
    for (int k = tid; k < chunk_n; k += 256) {
        int lo = 0, hi = NB;  // scl[lo] <= k < scl[hi]
        while (hi - lo > 1) {
            int mid = (lo + hi) >> 1;
            if (scl[mid] <= k) lo = mid; else hi = mid;
        }
        binned[base[lo] + (k - scl[lo])] = stage[k];
    }
}

// One WG per HALF bucket (512 nodes): filter the bucket's records by the
// local-id high bit, per-node count + scan in LDS, emit row_ptr/dis
// (sequential), scatter src into LDS colbuf, flush coalesced.
__global__ __launch_bounds__(512) void csr_bucket_kernel(
    const unsigned int* __restrict__ binned,
    const int* __restrict__ bucket_ptr,
    int* __restrict__ row_ptr, float* __restrict__ dis,
    int* __restrict__ col, int N) {
    __shared__ int cnt[512];
    __shared__ int cur[512];
    __shared__ int colbuf[MAXB];
    __shared__ int c0;      // records of this bucket with local < 512
    __shared__ int tot_s;   // records belonging to this half
    int b = blockIdx.x >> 1;
    int half = blockIdx.x & 1;
    int nbase = b * NPB + half * 512;
    int nlocal = min(512, N - nbase);
    int beg = bucket_ptr[b];
    int end = bucket_ptr[b + 1];
    int bsize = end - beg;
    int tid = threadIdx.x;

    cnt[tid] = 0;
    if (tid == 0) c0 = 0;
    __syncthreads();
    for (int k = tid; k < bsize; k += 512) {
        unsigned rec = binned[beg + k];
        int loc = (int)(rec & 1023u);
        if ((loc >> 9) == half) atomicAdd(&cnt[loc & 511], 1);
        unsigned long long m = __ballot(loc < 512);
        if ((tid & 63) == 0) atomicAdd(&c0, (int)__popcll(m));
    }
    __syncthreads();
    int v = cnt[tid];
    cur[tid] = v;
    __syncthreads();
    for (int off = 1; off < 512; off <<= 1) {
        int t = (tid >= off) ? cur[tid - off] : 0;
        __syncthreads();
        cur[tid] += t;
        __syncthreads();
    }
    int excl = cur[tid] - v;
    if (tid == 511) tot_s = cur[511];
    __syncthreads();
    int base_col = beg + (half ? c0 : 0);
    int tot = tot_s;
    if (tid < nlocal) {
        row_ptr[nbase + tid] = base_col + excl;
        dis[nbase + tid] = 1.0f / sqrtf((float)(v + 1));  // +1 self-loop
    }
    __syncthreads();
    cur[tid] = excl;
    __syncthreads();
    if (tot <= MAXB) {
        for (int k = tid; k < bsize; k += 512) {
            unsigned rec = binned[beg + k];
            int loc = (int)(rec & 1023u);
            if ((loc >> 9) == half) {
                int pos = atomicAdd(&cur[loc & 511], 1);
                colbuf[pos] = (int)(rec >> 10);
            }
        }
        __syncthreads();
        for (int k = tid; k < tot; k += 512) col[base_col + k] = colbuf[k];
    } else {  // statistical impossibility for this input; correctness fallback
        for (int k = tid; k < bsize; k += 512) {
            unsigned rec = binned[beg + k];
            int loc = (int)(rec & 1023u);
            if ((loc >> 9) == half) {
                int pos = atomicAdd(&cur[loc & 511], 1);
                col[base_col + pos] = (int)(rec >> 10);
            }
        }
    }
}

// PREACT: 0 = raw input (layer 1), 1 = bias + relu, 2 = bias only
// Writes fp16 xls split into OUT/C chunk tables of C features each.
template <int IN, int OUT, int C, int PREACT>
__global__ __launch_bounds__(256) void transform_kernel(
    const float* __restrict__ hin, const float* __restrict__ bias_prev,
    const float* __restrict__ W, const float* __restrict__ dis,
    __half* __restrict__ xls, int N) {
    __shared__ float sW[IN * OUT];
    __shared__ float sB[IN];
    for (int t = threadIdx.x; t < IN * OUT; t += blockDim.x) sW[t] = W[t];
    if (PREACT != 0) {
        for (int t = threadIdx.x; t < IN; t += blockDim.x) sB[t] = bias_prev[t];
    }
    __syncthreads();
    int i = blockIdx.x * blockDim.x + threadIdx.x;
    if (i >= N) return;

    float h[IN];
#pragma unroll
    for (int k = 0; k < IN; k++) {
        float v = hin[i * IN + k];
        if (PREACT != 0) {
            v += sB[k];
            if (PREACT == 1) v = fmaxf(v, 0.0f);
        }
        h[k] = v;
    }
    float d = dis[i];
    float o[OUT];
#pragma unroll
    for (int f = 0; f < OUT; f++) {
        float acc = 0.0f;
#pragma unroll
        for (int k = 0; k < IN; k++) acc = fmaf(h[k], sW[k * OUT + f], acc);
        o[f] = acc * d;  // pre-scaled by dis[i]
    }
    constexpr int NCH = OUT / C;
    constexpr int P = C / 2;
    __half2* x2 = (__half2*)xls;
#pragma unroll
    for (int c = 0; c < NCH; c++) {
#pragma unroll
        for (int k = 0; k < P; k++) {
            x2[(size_t)c * N * P + (size_t)i * P + k] =
                __floats2half2_rn(o[c * C + 2 * k], o[c * C + 2 * k + 1]);
        }
    }
}

// Pull gather, 2 threads per node: lane p in {0,1} handles edges beg+p,
// beg+p+2, ... unrolled x4 (8-edge stride). Pair partials combined via
// __shfl_xor(.,1); both lanes write alternating float2s of the output.
template <int C, int F, int COFF>
__global__ __launch_bounds__(256) void gather_kernel(
    const int* __restrict__ row_ptr, const int* __restrict__ col,
    const float* __restrict__ dis, const __half* __restrict__ xls,
    float* __restrict__ agg, int N) {
    int tid = blockIdx.x * blockDim.x + threadIdx.x;
    int i = tid >> 1;
    int p = tid & 1;
    if (i >= N) return;
    constexpr int P = C / 2;
    const __half2* x2 = (const __half2*)xls;
    float2 acc[P];
#pragma unroll
    for (int k = 0; k < P; k++) {
        if (p == 0) acc[k] = __half22float2(x2[(size_t)i * P + k]);  // self-loop
        else acc[k] = make_float2(0.0f, 0.0f);
    }
    int beg = row_ptr[i];
    int end = row_ptr[i + 1];
    int e = beg + p;
    for (; e + 6 < end; e += 8) {
        int c0 = col[e], c1 = col[e + 2], c2 = col[e + 4], c3 = col[e + 6];
        __half2 t0[P], t1[P], t2[P], t3[P];
#pragma unroll
        for (int k = 0; k < P; k++) t0[k] = x2[(size_t)c0 * P + k];
#pragma unroll
        for (int k = 0; k < P; k++) t1[k] = x2[(size_t)c1 * P + k];
#pragma unroll
        for (int k = 0; k < P; k++) t2[k] = x2[(size_t)c2 * P + k];
#pragma unroll
        for (int k = 0; k < P; k++) t3[k] = x2[(size_t)c3 * P + k];
#pragma unroll
        for (int k = 0; k < P; k++) {
            float2 a = __half22float2(t0[k]), bb = __half22float2(t1[k]);
            float2 cc = __half22float2(t2[k]), dd = __half22float2(t3[k]);
            acc[k].x += (a.x + bb.x) + (cc.x + dd.x);
            acc[k].y += (a.y + bb.y) + (cc.y + dd.y);
        }
    }
    for (; e < end; e += 2) {
        int c = col[e];
#pragma unroll
        for (int k = 0; k < P; k++) {
            float2 vv = __half22float2(x2[(size_t)c * P + k]);
            acc[k].x += vv.x;
            acc[k].y += vv.y;
        }
    }
    // combine pair partials (both lanes end with the full sum)
#pragma unroll
    for (int k = 0; k < P; k++) {
        acc[k].x += __shfl_xor(acc[k].x, 1);
        acc[k].y += __shfl_xor(acc[k].y, 1);
    }
    float d = dis[i];
    float2* ap = (float2*)(agg + (size_t)i * F + COFF);
#pragma unroll
    for (int k = 0; k < P; k++) {
        if ((k & 1) == p) ap[k] = make_float2(acc[k].x * d, acc[k].y * d);
    }
}

__global__ void final_kernel(const float* __restrict__ agg,
                             const float* __restrict__ b,
                             float* __restrict__ out, int total, int F) {
    int idx = blockIdx.x * blockDim.x + threadIdx.x;
    if (idx < total) {
        int f = idx % F;
        float v = agg[idx] + b[f];
        out[idx] = 1.0f / (1.0f + expf(-v));
    }
}

static inline size_t align_up(size_t v, size_t a) { return (v + a - 1) & ~(a - 1); }

extern "C" void kernel_launch(void* const* d_in, const int* in_sizes, int n_in,
                              void* d_out, int out_size, void* d_ws, size_t ws_size,
                              hipStream_t stream) {
    const float* x  = (const float*)d_in[0];
    const int*   ei = (const int*)d_in[1];
    const float* W1 = (const float*)d_in[2];
    const float* b1 = (const float*)d_in[3];
    const float* W2 = (const float*)d_in[4];
    const float* b2 = (const float*)d_in[5];
    const float* W3 = (const float*)d_in[6];
    const float* b3 = (const float*)d_in[7];
    const float* W4 = (const float*)d_in[8];
    const float* b4 = (const float*)d_in[9];
    float* out = (float*)d_out;

    const int N = in_sizes[0] / 12;
    const int E = in_sizes[1] / 2;
    const int* src = ei;       // edge_index[0]
    const int* dst = ei + E;   // edge_index[1]
    const int NB = (N + NPB - 1) / NPB;  // 196

    // Workspace carve-up (~62 MB)
    char* ws = (char*)d_ws;
    size_t off = 0;
    int* bucket_cnt = (int*)(ws + off);   off = align_up(off + (size_t)NB * 4, 256);
    int* bucket_ptr = (int*)(ws + off);   off = align_up(off + (size_t)(NB + 1) * 4, 256);
    int* bucket_cur = (int*)(ws + off);   off = align_up(off + (size_t)NB * 4, 256);
    int* row_ptr = (int*)(ws + off);      off = align_up(off + (size_t)(N + 1) * 4, 256);
    float* dis = (float*)(ws + off);      off = align_up(off + (size_t)N * 4, 256);
    unsigned int* binned = (unsigned int*)(ws + off); off = align_up(off + (size_t)E * 4, 256);
    int* col = (int*)(ws + off);          off = align_up(off + (size_t)E * 4, 256);
    __half* xls = (__half*)(ws + off);    off = align_up(off + (size_t)N * 16 * 2, 256);
    float* agg = (float*)(ws + off);      off = align_up(off + (size_t)N * 16 * 4, 256);
    (void)ws_size; (void)n_in; (void)out_size;

    const int B = 256;
    auto blocks = [&](long long n) { return (int)((n + B - 1) / B); };

    // --- CSR build via bucketed counting sort ----------------------------
    hipMemsetAsync(bucket_cnt, 0, (size_t)NB * sizeof(int), stream);
    hist_kernel<<<512, B, 0, stream>>>(dst, bucket_cnt, E, NB);
    bscan_kernel<<<1, 1024, 0, stream>>>(bucket_cnt, bucket_ptr, bucket_cur, row_ptr, NB, N, E);
    bin_kernel<<<(E + BIN_CHUNK - 1) / BIN_CHUNK, B, 0, stream>>>(src, dst, bucket_cur, binned, E, NB);
    csr_bucket_kernel<<<NB * 2, 512, 0, stream>>>(binned, bucket_ptr, row_ptr, dis, col, N);

    // Chunk-table bases (half units): chunk c of size C lives at c*N*C
    __half* x_c0 = xls;
    __half* x_c8 = xls + (size_t)N * 8;  // second chunk for C=8 layers
    __half* x_c6 = xls + (size_t)N * 6;  // second chunk for C=6 layer

    // --- Layer 1: x(12) @ W1 -> 16 (chunks 2x8) --------------------------
    transform_kernel<12, 16, 8, 0><<<blocks(N), B, 0, stream>>>(x, nullptr, W1, dis, xls, N);
    gather_kernel<8, 16, 0><<<blocks(2LL * N), B, 0, stream>>>(row_ptr, col, dis, x_c0, agg, N);
    gather_kernel<8, 16, 8><<<blocks(2LL * N), B, 0, stream>>>(row_ptr, col, dis, x_c8, agg, N);

    // --- Layer 2: relu(agg + b1)(16) @ W2 -> 8 (1x8) ---------------------
    transform_kernel<16, 8, 8, 1><<<blocks(N), B, 0, stream>>>(agg, b1, W2, dis, xls, N);
    gather_kernel<8, 8, 0><<<blocks(2LL * N), B, 0, stream>>>(row_ptr, col, dis, x_c0, agg, N);

    // --- Layer 3: (agg + b2)(8) @ W3 -> 16 (2x8, no relu) ----------------
    transform_kernel<8, 16, 8, 2><<<blocks(N), B, 0, stream>>>(agg, b2, W3, dis, xls, N);
    gather_kernel<8, 16, 0><<<blocks(2LL * N), B, 0, stream>>>(row_ptr, col, dis, x_c0, agg, N);
    gather_kernel<8, 16, 8><<<blocks(2LL * N), B, 0, stream>>>(row_ptr, col, dis, x_c8, agg, N);

    // --- Layer 4: relu(agg + b3)(16) @ W4 -> 12 (chunks 2x6) -------------
    transform_kernel<16, 12, 6, 1><<<blocks(N), B, 0, stream>>>(agg, b3, W4, dis, xls, N);
    gather_kernel<6, 12, 0><<<blocks(2LL * N), B, 0, stream>>>(row_ptr, col, dis, x_c0, agg, N);
    gather_kernel<6, 12, 6><<<blocks(2LL * N), B, 0, stream>>>(row_ptr, col, dis, x_c6, agg, N);

    // --- Epilogue: sigmoid(agg + b4) -> out ------------------------------
    final_kernel<<<blocks((long long)N * 12), B, 0, stream>>>(agg, b4, out, N * 12, 12);
}